// Round 12
// baseline (1901.486 us; speedup 1.0000x reference)
//
#include <hip/hip_runtime.h>
#include <cstdint>
#include <cstddef>

static constexpr int NPTS  = 4096;
static constexpr int NB    = 8;
static constexpr int NROWS = NB * NPTS;      // 32768
static constexpr int KNN   = 32;
static constexpr int SEG   = 96;             // survivor capacity per parity segment
static constexpr int LCAP  = 2 * SEG;        // 192 per row (3x64 for radix chunks)

typedef __attribute__((ext_vector_type(8))) short  bf16x8;
typedef __attribute__((ext_vector_type(4))) float  f32x4;
typedef unsigned short ushort_t;

// ---------------- utility: 64-bit shuffles built from 32-bit ----------------
__device__ __forceinline__ unsigned long long shfl_xor_u64(unsigned long long v, int m) {
  int lo = __shfl_xor((int)(unsigned)(v & 0xFFFFFFFFULL), m, 64);
  int hi = __shfl_xor((int)(unsigned)(v >> 32), m, 64);
  return ((unsigned long long)(unsigned)hi << 32) | (unsigned)lo;
}
__device__ __forceinline__ unsigned long long shfl_u64(unsigned long long v, int src) {
  int lo = __shfl((int)(unsigned)(v & 0xFFFFFFFFULL), src, 64);
  int hi = __shfl((int)(unsigned)(v >> 32), src, 64);
  return ((unsigned long long)(unsigned)hi << 32) | (unsigned)lo;
}
__device__ __forceinline__ ushort_t bf16_rne(float v) {
  unsigned u = __float_as_uint(v);
  return (ushort_t)((u + 0x7FFFu + ((u >> 16) & 1u)) >> 16);
}
// async global->LDS, 16B/lane; LDS side = uniform base + lane*16 (HW rule)
__device__ __forceinline__ void async16(void* lds, const void* g) {
  __builtin_amdgcn_global_load_lds(
      (const __attribute__((address_space(1))) unsigned int*)g,
      (__attribute__((address_space(3))) unsigned int*)lds, 16, 0, 0);
}

// ---------------- squared norms per point (ascending chain — key-critical) --
__global__ __launch_bounds__(256) void sqnorm_kernel(const float* __restrict__ x,
                                                     float* __restrict__ sq, int F) {
  int t = blockIdx.x * 256 + threadIdx.x;
  if (t >= NROWS) return;
  const float* p = x + (size_t)t * F;
  float s = 0.f;
  for (int f = 0; f < F; ++f) s = fmaf(p[f], p[f], s);
  sq[t] = s;
}

// ---------------- layer-1 prep: padded hi/lo bf16 split of x (F=3 -> 8) ----
__global__ __launch_bounds__(256) void prep3_kernel(const float* __restrict__ x,
                                                    ushort_t* __restrict__ hi3,
                                                    ushort_t* __restrict__ lo3) {
  int r = blockIdx.x * 256 + threadIdx.x;
  if (r >= NROWS) return;
#pragma unroll
  for (int f = 0; f < 8; ++f) {
    float v = (f < 3) ? x[(size_t)r * 3 + f] : 0.f;
    ushort_t h = bf16_rne(v);
    float hf = __uint_as_float((unsigned)h << 16);
    ushort_t l = bf16_rne(v - hf);
    hi3[(size_t)r * 8 + f] = h;
    lo3[(size_t)r * 8 + f] = l;
  }
}

// ---------------- per-batch max of sq ----------------
__global__ __launch_bounds__(256) void batchmax_kernel(const float* __restrict__ sq,
                                                       float* __restrict__ sqmax) {
  int b = blockIdx.x, t = threadIdx.x;
  float m = 0.f;
  for (int i = t; i < NPTS; i += 256) m = fmaxf(m, sq[b * NPTS + i]);
  for (int off = 32; off >= 1; off >>= 1) m = fmaxf(m, __shfl_xor(m, off, 64));
  __shared__ float ls[4];
  if ((t & 63) == 0) ls[t >> 6] = m;
  __syncthreads();
  if (t == 0) sqmax[b] = fmaxf(fmaxf(ls[0], ls[1]), fmaxf(ls[2], ls[3]));
}

// =====================================================================
// Fused screen + rerank.  3-term bf16 hi/lo MFMA (hh+hl+lh), certified
// eps = 6e-5*(si+sqmax)+1e-5 (R6/R8-validated).  1024 blocks x 256 thr;
// block owns 32 rows; waves = {row-half h} x {sub-parity p}.  Staging via
// global_load_lds width=16: per-lane GLOBAL addresses carry the fragment-
// major permutation, LDS dst is uniform-base+lane*16.  Pass 0: per-(lane,
// reg) top-2; cross-parity LDS merge -> exact union 2nd-min -> tau (R11-
// validated).  Pass 1: append survivors (d <= tau+2eps) to per-row LDS
// lists (2 parity segments x SEG).  Tail: each wave reranks 8 rows with
// bit-identical fp32 chains + 44-bit lex radix-select, writes idx_out.
// Segment overflow -> flag row; knn_fallback does the exact full scan.
// =====================================================================
template <int F>
__global__ __launch_bounds__(256, 3)
void knn_screen(const ushort_t* __restrict__ hi,
                const ushort_t* __restrict__ lo,
                const float* __restrict__ x,
                const float* __restrict__ sq,
                const float* __restrict__ sqmax,
                int* __restrict__ flags,
                ushort_t* __restrict__ idx_out) {
  __shared__ __attribute__((aligned(16))) ushort_t chi_f[(F == 64) ? 8192 : 1024];
  __shared__ __attribute__((aligned(16))) ushort_t clo_f[(F == 64) ? 8192 : 1024];
  __shared__ float csq[128];
  __shared__ float exch3[(F == 64) ? 1 : 2048];
  __shared__ ushort_t lists[32 * LCAP];
  __shared__ int cnts[32][2];

  const int t = threadIdx.x, wave = t >> 6, lane = t & 63;
  const int l16 = lane & 15, quad = lane >> 4;
  const int h = wave >> 1, p = wave & 1;
  const int bid = blockIdx.x;
  const int b   = bid & 7;                  // XCD-affine batch
  const int rg  = bid >> 3;                 // 0..127 row-group (32 rows)
  const int i0w = rg * 32 + h * 16;         // wave's first row (in batch)
  const size_t base = (size_t)b * NPTS;
  constexpr int RS = (F == 64) ? 64 : 8;
  const ushort_t* hib = hi + base * RS;
  const ushort_t* lob = lo + base * RS;
  const float* sqb = sq + base;
  const float* xb  = x + base * F;
  const float sqm = sqmax[b];

  const bf16x8 z8 = {0, 0, 0, 0, 0, 0, 0, 0};
  bf16x8 ahi[2] = {z8, z8}, alo[2] = {z8, z8};
  if constexpr (F == 64) {
#pragma unroll
    for (int kb = 0; kb < 2; ++kb) {
      ahi[kb] = *(const bf16x8*)(hib + (size_t)(i0w + l16) * 64 + kb * 32 + quad * 8);
      alo[kb] = *(const bf16x8*)(lob + (size_t)(i0w + l16) * 64 + kb * 32 + quad * 8);
    }
  } else {
    if (quad == 0) {
      ahi[0] = *(const bf16x8*)(hib + (size_t)(i0w + l16) * 8);
      alo[0] = *(const bf16x8*)(lob + (size_t)(i0w + l16) * 8);
    }
  }
  float sqi4[4];
#pragma unroll
  for (int reg = 0; reg < 4; ++reg) sqi4[reg] = sqb[i0w + quad * 4 + reg];

  float t1[4], t2[4], tinf4[4];
  int cnt4[4] = {0, 0, 0, 0};
#pragma unroll
  for (int reg = 0; reg < 4; ++reg) { t1[reg] = 3.4e38f; t2[reg] = 3.4e38f; tinf4[reg] = 0.f; }

  for (int pass = 0; pass < 2; ++pass) {
    // DMA source pointers for this wave's 4 issues per array (reset per pass)
    const char* gph[4];
    const char* gpl[4];
    if constexpr (F == 64) {
#pragma unroll
      for (int k = 0; k < 4; ++k) {
        int i = wave * 4 + k, sub = i >> 1, kb = i & 1;
        size_t o = (size_t)(sub * 16 + l16) * 128 + kb * 64 + quad * 16;
        gph[k] = (const char*)hib + o;
        gpl[k] = (const char*)lob + o;
      }
    }
    for (int tile = 0; tile < 32; ++tile) {
      __syncthreads();
      if constexpr (F == 64) {
#pragma unroll
        for (int k = 0; k < 4; ++k) {
          int i = wave * 4 + k;
          async16(&chi_f[i * 512], gph[k]);
          async16(&clo_f[i * 512], gpl[k]);
          gph[k] += 16384;
          gpl[k] += 16384;
        }
        if (t < 128) csq[t] = sqb[tile * 128 + t];
      } else {
        if (t < 128) {
          *(bf16x8*)&chi_f[t * 8] = *(const bf16x8*)(hib + (size_t)(tile * 128 + t) * 8);
          *(bf16x8*)&clo_f[t * 8] = *(const bf16x8*)(lob + (size_t)(tile * 128 + t) * 8);
          csq[t] = sqb[tile * 128 + t];
        }
      }
      __syncthreads();

#pragma unroll 2
      for (int s = 0; s < 4; ++s) {
        const int sub = p * 4 + s;
        const int jl = sub * 16 + l16;
        f32x4 acc = {0.f, 0.f, 0.f, 0.f};
        if constexpr (F == 64) {
          bf16x8 bh0 = *(const bf16x8*)&chi_f[(((sub * 2 + 0) << 6) + lane) << 3];
          bf16x8 bh1 = *(const bf16x8*)&chi_f[(((sub * 2 + 1) << 6) + lane) << 3];
          bf16x8 bl0 = *(const bf16x8*)&clo_f[(((sub * 2 + 0) << 6) + lane) << 3];
          bf16x8 bl1 = *(const bf16x8*)&clo_f[(((sub * 2 + 1) << 6) + lane) << 3];
          acc = __builtin_amdgcn_mfma_f32_16x16x32_bf16(ahi[0], bh0, acc, 0, 0, 0);
          acc = __builtin_amdgcn_mfma_f32_16x16x32_bf16(ahi[1], bh1, acc, 0, 0, 0);
          acc = __builtin_amdgcn_mfma_f32_16x16x32_bf16(ahi[0], bl0, acc, 0, 0, 0);
          acc = __builtin_amdgcn_mfma_f32_16x16x32_bf16(ahi[1], bl1, acc, 0, 0, 0);
          acc = __builtin_amdgcn_mfma_f32_16x16x32_bf16(alo[0], bh0, acc, 0, 0, 0);
          acc = __builtin_amdgcn_mfma_f32_16x16x32_bf16(alo[1], bh1, acc, 0, 0, 0);
        } else {
          bf16x8 bh = (quad == 0) ? *(const bf16x8*)&chi_f[jl * 8] : z8;
          bf16x8 bl = (quad == 0) ? *(const bf16x8*)&clo_f[jl * 8] : z8;
          acc = __builtin_amdgcn_mfma_f32_16x16x32_bf16(ahi[0], bh, acc, 0, 0, 0);
          acc = __builtin_amdgcn_mfma_f32_16x16x32_bf16(ahi[0], bl, acc, 0, 0, 0);
          acc = __builtin_amdgcn_mfma_f32_16x16x32_bf16(alo[0], bh, acc, 0, 0, 0);
        }
        const float cs = csq[jl];
        const int jg = tile * 128 + jl;
#pragma unroll
        for (int reg = 0; reg < 4; ++reg) {   // C/D: col=l16 (cand), row=quad*4+reg
          float d = fmaf(-2.f, acc[reg], sqi4[reg] + cs);
          if (pass == 0) {
            float lo_ = fminf(d, t1[reg]);
            float hi_ = fmaxf(d, t1[reg]);
            t1[reg] = lo_;
            t2[reg] = fminf(t2[reg], hi_);
          } else {
            bool keep = d <= tinf4[reg];
            unsigned long long mask = __ballot(keep);
            unsigned qm = (unsigned)((mask >> (quad * 16)) & 0xFFFFULL);
            int rank = __popc(qm & ((1u << l16) - 1u));
            if (keep) {
              int pos = cnt4[reg] + rank;
              if (pos < SEG)
                lists[(h * 16 + quad * 4 + reg) * LCAP + p * SEG + pos] = (ushort_t)jg;
            }
            cnt4[reg] += __popc(qm);
          }
        }
      }
    }
    if (pass == 0) {
      // ---- cross-parity merge of per-(lane,reg) top-2 -> exact union tau ----
      float* exch = (F == 64) ? (float*)chi_f : exch3;   // 2048 floats
      __syncthreads();
#pragma unroll
      for (int reg = 0; reg < 4; ++reg) {
        exch[(wave * 64 + lane) * 4 + reg] = t1[reg];
        exch[1024 + (wave * 64 + lane) * 4 + reg] = t2[reg];
      }
      __syncthreads();
      const int pw = wave ^ 1;                           // partner parity, same rows
#pragma unroll
      for (int reg = 0; reg < 4; ++reg) {
        float o1 = exch[(pw * 64 + lane) * 4 + reg];
        float o2 = exch[1024 + (pw * 64 + lane) * 4 + reg];
        float m2 = fminf(fmaxf(t1[reg], o1), fminf(t2[reg], o2)); // union 2nd-min
        float v = m2;
#pragma unroll
        for (int off = 1; off < 16; off <<= 1)
          v = fmaxf(v, __shfl_xor(v, off, 64));          // within-quad reduce
        float eps = 6e-5f * (sqi4[reg] + sqm) + 1e-5f;
        tinf4[reg] = v + 2.f * eps;
      }
    }
  }

  // ---- publish counts ----
  __syncthreads();
  if (l16 == 0) {
#pragma unroll
    for (int reg = 0; reg < 4; ++reg) cnts[h * 16 + quad * 4 + reg][p] = cnt4[reg];
  }
  __syncthreads();

  // ---- fused exact rerank: 8 rows per wave ----
  for (int rr = 0; rr < 8; ++rr) {
    const int rl = wave * 8 + rr;          // local row 0..31
    const int gi = rg * 32 + rl;           // row within batch
    const int grow = (int)base + gi;       // global row
    const int n0 = cnts[rl][0], n1 = cnts[rl][1];
    if (n0 > SEG || n1 > SEG) {
      if (lane == 0) flags[grow] = 1;
      continue;
    }
    if (lane == 0) flags[grow] = 0;
    const float sqi = sqb[gi];

    float4 q[(F == 64) ? 16 : 1];
    float qx = 0.f, qy = 0.f, qz = 0.f;
    if constexpr (F == 64) {
#pragma unroll
      for (int c4 = 0; c4 < 16; ++c4)
        q[c4] = *(const float4*)(xb + (size_t)gi * 64 + c4 * 4);
    } else {
      qx = xb[(size_t)gi * 3 + 0];
      qy = xb[(size_t)gi * 3 + 1];
      qz = xb[(size_t)gi * 3 + 2];
    }

    const int n = n0 + n1;
    unsigned long long vk[3];
#pragma unroll
    for (int s = 0; s < 3; ++s) {
      int li = s * 64 + lane;
      unsigned long long v = 0xFFFFFFFFFFFULL;        // sentinel > any real
      if (li < n) {
        int j = (li < n0) ? lists[rl * LCAP + li]
                          : lists[rl * LCAP + SEG + (li - n0)];
        float d;
        if constexpr (F == 64) {
          const float4* xj = (const float4*)(xb + (size_t)j * 64);
          float dot = 0.f;
#pragma unroll
          for (int c4 = 0; c4 < 16; ++c4) {
            float4 c = xj[c4];
            dot = fmaf(q[c4].x, c.x, dot);
            dot = fmaf(q[c4].y, c.y, dot);
            dot = fmaf(q[c4].z, c.z, dot);
            dot = fmaf(q[c4].w, c.w, dot);
          }
          d = fmaf(-2.f, dot, sqi + sqb[j]);
        } else {
          const float* xj = xb + (size_t)j * 3;
          float dot = fmaf(qz, xj[2], fmaf(qy, xj[1], qx * xj[0]));
          d = fmaf(-2.f, dot, sqi + sqb[j]);
        }
        unsigned u  = __float_as_uint(d);
        unsigned ck = (u & 0x80000000u) ? ~u : (u | 0x80000000u);
        v = ((unsigned long long)ck << 12) | (unsigned)j;
      }
      vk[s] = v;
    }
    // 44-bit radix-select of the exact 32nd-smallest lex-(dist,idx) value
    unsigned long long prefix = 0;
    int need = 32;
    for (int bit = 43; bit >= 0; --bit) {
      unsigned long long hm = (bit == 43) ? 0ULL
          : (~((1ULL << (bit + 1)) - 1ULL) & 0xFFFFFFFFFFFULL);
      int cnt0 = 0;
#pragma unroll
      for (int s = 0; s < 3; ++s) {
        bool a = ((vk[s] ^ prefix) & hm) == 0ULL;
        bool z = ((vk[s] >> bit) & 1ULL) == 0ULL;
        cnt0 += (int)__popcll(__ballot(a && z));
      }
      if (cnt0 < need) { need -= cnt0; prefix |= 1ULL << bit; }
    }
    int prev = 0;
#pragma unroll
    for (int s = 0; s < 3; ++s) {
      bool sel = vk[s] <= prefix;
      unsigned long long m = __ballot(sel);
      int rank = (int)__popcll(m & ((1ULL << lane) - 1ULL));
      if (sel)
        idx_out[(size_t)grow * KNN + prev + rank] = (ushort_t)(vk[s] & 0xFFFULL);
      prev += (int)__popcll(m);
    }
  }
}

// =====================================================================
// Fallback: exact full scan with validated ballot-insert, only for rows
// flagged by the screen (segment overflow). Expected: none -> fast exit.
// =====================================================================
template <int F>
__global__ __launch_bounds__(256, 4)
void knn_fallback(const float* __restrict__ x, const float* __restrict__ sq,
                  const int* __restrict__ flags,
                  ushort_t* __restrict__ idx_out) {
  const int t = threadIdx.x, wave = t >> 6, lane = t & 63;
  const int row = blockIdx.x * 4 + wave;      // 0..32767
  if (flags[row] == 0) return;                // wave-uniform
  const int b = row >> 12;
  const int i = row & (NPTS - 1);
  const float* xb  = x + (size_t)b * NPTS * F;
  const float* sqb = sq + ((size_t)b << 12);
  const float sqi = sqb[i];

  float4 q[(F == 64) ? 16 : 1];
  float qx = 0.f, qy = 0.f, qz = 0.f;
  if constexpr (F == 64) {
#pragma unroll
    for (int c4 = 0; c4 < 16; ++c4)
      q[c4] = *(const float4*)(xb + (size_t)i * 64 + c4 * 4);
  } else {
    qx = xb[(size_t)i * 3 + 0];
    qy = xb[(size_t)i * 3 + 1];
    qz = xb[(size_t)i * 3 + 2];
  }

  unsigned long long ent = (0xFFFFFFFFFFFULL << 5) | (unsigned long long)(lane & 31);
  unsigned long long M   = (0xFFFFFFFFFFFULL << 5) | 31ULL;
  for (int c0 = 0; c0 < NPTS; c0 += 64) {
    const int j = c0 + lane;
    float d;
    if constexpr (F == 64) {
      const float4* xj = (const float4*)(xb + (size_t)j * 64);
      float dot = 0.f;
#pragma unroll
      for (int c4 = 0; c4 < 16; ++c4) {
        float4 c = xj[c4];
        dot = fmaf(q[c4].x, c.x, dot);
        dot = fmaf(q[c4].y, c.y, dot);
        dot = fmaf(q[c4].z, c.z, dot);
        dot = fmaf(q[c4].w, c.w, dot);
      }
      d = fmaf(-2.f, dot, sqi + sqb[j]);
    } else {
      const float* xj = xb + (size_t)j * 3;
      float dot = fmaf(qz, xj[2], fmaf(qy, xj[1], qx * xj[0]));
      d = fmaf(-2.f, dot, sqi + sqb[j]);
    }
    unsigned u  = __float_as_uint(d);
    unsigned ck = (u & 0x80000000u) ? ~u : (u | 0x80000000u);
    unsigned long long cq = ((unsigned long long)ck << 12) | (unsigned)j;
    unsigned long long mask = __ballot(cq < (M >> 5));
    while (mask) {
      const int src = __builtin_ctzll(mask);
      mask &= mask - 1;
      const unsigned long long bq = shfl_u64(cq, src);
      if (bq < (M >> 5)) {
        const unsigned slot = (unsigned)(M & 31ULL);
        if ((unsigned)(lane & 31) == slot) ent = (bq << 5) | slot;
        unsigned long long v = ent;
#pragma unroll
        for (int off = 16; off >= 1; off >>= 1) {
          unsigned long long w2 = shfl_xor_u64(v, off);
          v = (v > w2) ? v : w2;
        }
        M = v;
      }
    }
  }
  if (lane < 32)
    idx_out[(size_t)row * KNN + lane] = (ushort_t)((ent >> 5) & 0xFFFULL);
}

// ---------------- per-node P = x.Wbot ; C = x.(Wtop-Wbot) + b ----------------
__global__ __launch_bounds__(256) void mlp_pc_kernel(const float* __restrict__ xin,
                                                     const float* __restrict__ W,
                                                     const float* __restrict__ bias,
                                                     float* __restrict__ P,
                                                     float* C,
                                                     int F, int O, int total) {
  int t = blockIdx.x * 256 + threadIdx.x;
  if (t >= total) return;
  int n = t / O, o = t % O;
  const float* xr = xin + (size_t)n * F;
  const float* Wt = W + o;
  const float* Wb = W + (size_t)F * O + o;
  float p = 0.f, c = 0.f;
  for (int f = 0; f < F; ++f) {
    float a  = xr[f];
    float wt = Wt[(size_t)f * O];
    float wb = Wb[(size_t)f * O];
    p = fmaf(a, wb, p);
    c = fmaf(a, wt - wb, c);
  }
  P[t] = p;
  C[t] = c + bias[o];
}

// ---------------- fused: h += max_k P[idx_k]  +  BN partial sums (O=64) -----
__global__ __launch_bounds__(256, 8)
void aggregate_bn_kernel(const ushort_t* __restrict__ idx,
                         const float* __restrict__ P,
                         float* h, double2* __restrict__ partial) {
  const int t = threadIdx.x, wave = t >> 6, lane = t & 63;
  double s = 0.0, s2 = 0.0;
  for (int r = blockIdx.x * 4 + wave; r < NROWS; r += 16384) {
    const ushort_t* ix = idx + (size_t)r * KNN;
    const int rowbase = (r >> 12) << 12;
    float m = -3.402823466e+38f;
#pragma unroll 8
    for (int k = 0; k < KNN; ++k) {
      int jg = rowbase + ix[k];
      m = fmaxf(m, P[(size_t)jg * 64 + lane]);
    }
    float hv = h[(size_t)r * 64 + lane] + m;
    h[(size_t)r * 64 + lane] = hv;
    float v = fmaxf(hv, 0.f);
    s += v;
    s2 += (double)v * v;
  }
  __shared__ double ls[4][64], ls2[4][64];
  ls[wave][lane] = s;
  ls2[wave][lane] = s2;
  __syncthreads();
  if (wave == 0) {
    double a = ls[0][lane] + ls[1][lane] + ls[2][lane] + ls[3][lane];
    double bb = ls2[0][lane] + ls2[1][lane] + ls2[2][lane] + ls2[3][lane];
    double2 o; o.x = a; o.y = bb;
    partial[blockIdx.x * 64 + lane] = o;
  }
}

// ---------------- BN finalize: 64 blocks, one channel each ----------------
__global__ __launch_bounds__(64) void bn_finalize_kernel(const double2* __restrict__ partial,
                                                         float* __restrict__ stats) {
  const int c = blockIdx.x, t = threadIdx.x;
  double s = 0.0, s2 = 0.0;
  for (int p = t; p < 4096; p += 64) {
    double2 v = partial[p * 64 + c];
    s += v.x;
    s2 += v.y;
  }
  __shared__ double ss[64], ss2[64];
  ss[t] = s; ss2[t] = s2;
  __syncthreads();
  for (int st = 32; st; st >>= 1) {
    if (t < st) { ss[t] += ss[t + st]; ss2[t] += ss2[t + st]; }
    __syncthreads();
  }
  if (t == 0) {
    double mean = ss[0] / (double)NROWS;
    double var  = ss2[0] / (double)NROWS - mean * mean;
    stats[c]      = (float)mean;
    stats[64 + c] = (float)(1.0 / sqrt(var + 1e-5));
  }
}

// ---------------- fused: BN apply + hi/lo bf16 split of the output ----------
__global__ __launch_bounds__(256) void bn_apply_fused(const float* h,
                                                      const float* __restrict__ stats,
                                                      const float* __restrict__ g,
                                                      const float* __restrict__ be,
                                                      float* out,
                                                      ushort_t* __restrict__ hi,
                                                      ushort_t* __restrict__ lo,
                                                      int total) {
  int t = blockIdx.x * 256 + threadIdx.x;
  if (t >= total) return;
  int ch = t & 63;
  float v = fmaxf(h[t], 0.f);
  float o = (v - stats[ch]) * stats[64 + ch] * g[ch] + be[ch];
  out[t] = o;
  ushort_t hh = bf16_rne(o);
  float hf = __uint_as_float((unsigned)hh << 16);
  ushort_t ll = bf16_rne(o - hf);
  hi[t] = hh;
  lo[t] = ll;
}

// ---------------- plain aggregate for O=3 (layer 3) ----------------
__global__ __launch_bounds__(256) void aggregate_kernel(const ushort_t* __restrict__ idx,
                                                        const float* __restrict__ P,
                                                        float* h, int O, int total) {
  int t = blockIdx.x * 256 + threadIdx.x;
  if (t >= total) return;
  int n = t / O, o = t % O;
  const ushort_t* ix = idx + (size_t)n * KNN;
  const int rowbase = (n >> 12) << 12;
  float m = -3.402823466e+38f;
  for (int k = 0; k < KNN; ++k) {
    int jg = rowbase + ix[k];
    float v = P[(size_t)jg * O + o];
    m = fmaxf(m, v);
  }
  h[t] = h[t] + m;
}

// ---------------- write h3 to out + per-block loss partials ----------------
__global__ __launch_bounds__(256) void final_kernel(const float* __restrict__ h3,
                                                    const float* __restrict__ target,
                                                    float* __restrict__ out,
                                                    double* __restrict__ partial) {
  double s = 0.0;
  for (int t = blockIdx.x * 256 + threadIdx.x; t < NROWS * 3; t += 256 * 256) {
    float v = h3[t];
    out[t] = v;
    float d = v - target[t];
    s += (double)d * d;
  }
  __shared__ double ls[256];
  int t = threadIdx.x;
  ls[t] = s;
  __syncthreads();
  for (int st = 128; st; st >>= 1) {
    if (t < st) ls[t] += ls[t + st];
    __syncthreads();
  }
  if (t == 0) partial[blockIdx.x] = ls[0];
}

__global__ __launch_bounds__(256) void loss_kernel(const double* __restrict__ partial,
                                                   float* __restrict__ out) {
  int t = threadIdx.x;
  __shared__ double ls[256];
  ls[t] = partial[t];
  __syncthreads();
  for (int st = 128; st; st >>= 1) {
    if (t < st) ls[t] += ls[t + st];
    __syncthreads();
  }
  if (t == 0) out[NROWS * 3] = (float)(ls[0] / (double)(NROWS * 3));
}

// ---------------- driver ----------------
extern "C" void kernel_launch(void* const* d_in, const int* in_sizes, int n_in,
                              void* d_out, int out_size, void* d_ws, size_t ws_size,
                              hipStream_t stream) {
  const float* x   = (const float*)d_in[0];
  const float* tgt = (const float*)d_in[1];
  const float* W1  = (const float*)d_in[2];
  const float* b1  = (const float*)d_in[3];
  const float* g1  = (const float*)d_in[4];
  const float* be1 = (const float*)d_in[5];
  const float* W2  = (const float*)d_in[6];
  const float* b2  = (const float*)d_in[7];
  const float* g2  = (const float*)d_in[8];
  const float* be2 = (const float*)d_in[9];
  const float* W3  = (const float*)d_in[10];
  const float* b3  = (const float*)d_in[11];
  float* out = (float*)d_out;

  char* ws = (char*)d_ws;
  size_t off = 0;
  float* sq    = (float*)(ws + off); off += (size_t)NROWS * 4;            // 128 KB
  ushort_t* idxb = (ushort_t*)(ws + off); off += (size_t)NROWS * KNN * 2; // 2 MB
  float* P     = (float*)(ws + off); off += (size_t)NROWS * 64 * 4;       // 8 MB
  float* CA    = (float*)(ws + off); off += (size_t)NROWS * 64 * 4;       // 8 MB
  float* CB    = (float*)(ws + off); off += (size_t)NROWS * 64 * 4;       // 8 MB
  int*   flags = (int*)(ws + off);   off += (size_t)NROWS * 4;            // 128 KB
  double2* partBN = (double2*)(ws + off); off += (size_t)4096 * 64 * 16;  // 4 MB
  float* stats = (float*)(ws + off); off += 256 * 4;
  float* sqmax = (float*)(ws + off); off += 64;
  double* part = (double*)(ws + off); off += 256 * 8;

  // Aliases (lifetime-disjoint):
  ushort_t* hi64 = (ushort_t*)P;                 // bf16 hi/lo live bn_apply_fused -> screen
  ushort_t* lo64 = hi64 + (size_t)NROWS * 64;
  ushort_t* hi3 = (ushort_t*)CB;                 // padded F=3 split, layer 1 only
  ushort_t* lo3 = hi3 + (size_t)NROWS * 8;

  const int T64 = NROWS * 64;
  const int T3  = NROWS * 3;

  // ---- layer 1 (F=3 -> 64) ----
  sqnorm_kernel<<<NROWS / 256, 256, 0, stream>>>(x, sq, 3);
  prep3_kernel<<<NROWS / 256, 256, 0, stream>>>(x, hi3, lo3);
  batchmax_kernel<<<NB, 256, 0, stream>>>(sq, sqmax);
  knn_screen<3><<<1024, 256, 0, stream>>>(hi3, lo3, x, sq, sqmax, flags, idxb);
  knn_fallback<3><<<NROWS / 4, 256, 0, stream>>>(x, sq, flags, idxb);
  mlp_pc_kernel<<<T64 / 256, 256, 0, stream>>>(x, W1, b1, P, CA, 3, 64, T64);
  aggregate_bn_kernel<<<4096, 256, 0, stream>>>(idxb, P, CA, partBN);
  bn_finalize_kernel<<<64, 64, 0, stream>>>(partBN, stats);
  bn_apply_fused<<<T64 / 256, 256, 0, stream>>>(CA, stats, g1, be1, CA, hi64, lo64, T64);

  // ---- layer 2 (F=64 -> 64) ----
  sqnorm_kernel<<<NROWS / 256, 256, 0, stream>>>(CA, sq, 64);
  batchmax_kernel<<<NB, 256, 0, stream>>>(sq, sqmax);
  knn_screen<64><<<1024, 256, 0, stream>>>(hi64, lo64, CA, sq, sqmax, flags, idxb);
  knn_fallback<64><<<NROWS / 4, 256, 0, stream>>>(CA, sq, flags, idxb);
  mlp_pc_kernel<<<T64 / 256, 256, 0, stream>>>(CA, W2, b2, P, CB, 64, 64, T64);
  aggregate_bn_kernel<<<4096, 256, 0, stream>>>(idxb, P, CB, partBN);
  bn_finalize_kernel<<<64, 64, 0, stream>>>(partBN, stats);
  bn_apply_fused<<<T64 / 256, 256, 0, stream>>>(CB, stats, g2, be2, CB, hi64, lo64, T64);

  // ---- layer 3 (F=64 -> 3) ----
  sqnorm_kernel<<<NROWS / 256, 256, 0, stream>>>(CB, sq, 64);
  batchmax_kernel<<<NB, 256, 0, stream>>>(sq, sqmax);
  knn_screen<64><<<1024, 256, 0, stream>>>(hi64, lo64, CB, sq, sqmax, flags, idxb);
  knn_fallback<64><<<NROWS / 4, 256, 0, stream>>>(CB, sq, flags, idxb);
  mlp_pc_kernel<<<T3 / 256, 256, 0, stream>>>(CB, W3, b3, P, CA, 64, 3, T3);
  aggregate_kernel<<<T3 / 256, 256, 0, stream>>>(idxb, P, CA, 3, T3);

  // ---- output + loss ----
  final_kernel<<<256, 256, 0, stream>>>(CA, tgt, out, part);
  loss_kernel<<<1, 256, 0, stream>>>(part, out);
}

// Round 13
// 1666.651 us; speedup vs baseline: 1.1409x; 1.1409x over previous
//
#include <hip/hip_runtime.h>
#include <cstdint>
#include <cstddef>

static constexpr int NPTS  = 4096;
static constexpr int NB    = 8;
static constexpr int NROWS = NB * NPTS;      // 32768
static constexpr int KNN   = 32;
static constexpr int CAP   = 192;            // survivor list capacity per row

typedef __attribute__((ext_vector_type(8))) short  bf16x8;
typedef __attribute__((ext_vector_type(4))) float  f32x4;
typedef unsigned short ushort_t;

// ---------------- utility: 64-bit shuffles built from 32-bit ----------------
__device__ __forceinline__ unsigned long long shfl_xor_u64(unsigned long long v, int m) {
  int lo = __shfl_xor((int)(unsigned)(v & 0xFFFFFFFFULL), m, 64);
  int hi = __shfl_xor((int)(unsigned)(v >> 32), m, 64);
  return ((unsigned long long)(unsigned)hi << 32) | (unsigned)lo;
}
__device__ __forceinline__ unsigned long long shfl_u64(unsigned long long v, int src) {
  int lo = __shfl((int)(unsigned)(v & 0xFFFFFFFFULL), src, 64);
  int hi = __shfl((int)(unsigned)(v >> 32), src, 64);
  return ((unsigned long long)(unsigned)hi << 32) | (unsigned)lo;
}
__device__ __forceinline__ ushort_t bf16_rne(float v) {
  unsigned u = __float_as_uint(v);
  return (ushort_t)((u + 0x7FFFu + ((u >> 16) & 1u)) >> 16);
}

// ---------------- squared norms per point (ascending chain — key-critical) --
__global__ __launch_bounds__(256) void sqnorm_kernel(const float* __restrict__ x,
                                                     float* __restrict__ sq, int F) {
  int t = blockIdx.x * 256 + threadIdx.x;
  if (t >= NROWS) return;
  const float* p = x + (size_t)t * F;
  float s = 0.f;
  for (int f = 0; f < F; ++f) s = fmaf(p[f], p[f], s);
  sq[t] = s;
}

// ---------------- layer-1 prep: padded hi/lo bf16 split of x (F=3 -> 8) ----
__global__ __launch_bounds__(256) void prep3_kernel(const float* __restrict__ x,
                                                    ushort_t* __restrict__ hi3,
                                                    ushort_t* __restrict__ lo3) {
  int r = blockIdx.x * 256 + threadIdx.x;
  if (r >= NROWS) return;
#pragma unroll
  for (int f = 0; f < 8; ++f) {
    float v = (f < 3) ? x[(size_t)r * 3 + f] : 0.f;
    ushort_t h = bf16_rne(v);
    float hf = __uint_as_float((unsigned)h << 16);
    ushort_t l = bf16_rne(v - hf);
    hi3[(size_t)r * 8 + f] = h;
    lo3[(size_t)r * 8 + f] = l;
  }
}

// ---------------- per-batch max of sq ----------------
__global__ __launch_bounds__(256) void batchmax_kernel(const float* __restrict__ sq,
                                                       float* __restrict__ sqmax) {
  int b = blockIdx.x, t = threadIdx.x;
  float m = 0.f;
  for (int i = t; i < NPTS; i += 256) m = fmaxf(m, sq[b * NPTS + i]);
  for (int off = 32; off >= 1; off >>= 1) m = fmaxf(m, __shfl_xor(m, off, 64));
  __shared__ float ls[4];
  if ((t & 63) == 0) ls[t >> 6] = m;
  __syncthreads();
  if (t == 0) sqmax[b] = fmaxf(fmaxf(ls[0], ls[1]), fmaxf(ls[2], ls[3]));
}

// =====================================================================
// Screen (R9-validated, 281 us/dispatch measured): 3-term bf16 hi/lo MFMA
// (hh+hl+lh) + certified eps = 6e-5*(si+sqmax)+1e-5.  512 blocks x 256
// thr; block owns 64 rows, wave owns its 16 (A-frags read once), 128-cand
// LDS tiles (FPS=72 stride; conflicts are ~2-way, near-free per m136).
// Pass 0: per-(lane,reg) top-2 over the lane's 256 cands -> tau = max
// over quad's 16 lanes of 2nd-min (>=32 cands <= tau); tinf = tau+2eps
// admits every exact lex-(dist,idx) top-32 member.  Pass 1: recompute,
// append survivors via quad-ballot rank (no LDS atomics).
// =====================================================================
template <int F>
__global__ __launch_bounds__(256, 4)
void knn_screen(const ushort_t* __restrict__ hi,
                const ushort_t* __restrict__ lo,
                const float* __restrict__ sq,
                const float* __restrict__ sqmax,
                int* __restrict__ gcnt,
                ushort_t* __restrict__ glist) {
  constexpr int FPS = (F == 64) ? 72 : 8;   // LDS row stride (shorts)
  constexpr int RS  = (F == 64) ? 64 : 8;   // global row stride (shorts)
  __shared__ __attribute__((aligned(16))) ushort_t chi[128 * FPS];
  __shared__ __attribute__((aligned(16))) ushort_t clo[128 * FPS];
  __shared__ float csq[128];

  const int t = threadIdx.x, wave = t >> 6, lane = t & 63;
  const int l16 = lane & 15, quad = lane >> 4;
  const int bid = blockIdx.x;
  const int b   = bid & 7;                         // XCD-affine batch
  const int i0w = ((bid >> 3) << 6) + (wave << 4); // this wave's 16 rows
  const size_t base = (size_t)b * NPTS;
  const ushort_t* hib = hi + base * RS;
  const ushort_t* lob = lo + base * RS;
  const float* sqb = sq + base;
  const float sqm = sqmax[b];

  const bf16x8 z8 = {0, 0, 0, 0, 0, 0, 0, 0};
  bf16x8 ahi[2] = {z8, z8}, alo[2] = {z8, z8};
  if constexpr (F == 64) {
#pragma unroll
    for (int kb = 0; kb < 2; ++kb) {
      ahi[kb] = *(const bf16x8*)(hib + (size_t)(i0w + l16) * 64 + kb * 32 + quad * 8);
      alo[kb] = *(const bf16x8*)(lob + (size_t)(i0w + l16) * 64 + kb * 32 + quad * 8);
    }
  } else {
    if (quad == 0) {
      ahi[0] = *(const bf16x8*)(hib + (size_t)(i0w + l16) * 8);
      alo[0] = *(const bf16x8*)(lob + (size_t)(i0w + l16) * 8);
    }
  }
  float sqi4[4];
#pragma unroll
  for (int reg = 0; reg < 4; ++reg) sqi4[reg] = sqb[i0w + quad * 4 + reg];

  float t1[4], t2[4], tinf4[4];
  int cnt4[4] = {0, 0, 0, 0};
#pragma unroll
  for (int reg = 0; reg < 4; ++reg) { t1[reg] = 3.4e38f; t2[reg] = 3.4e38f; tinf4[reg] = 0.f; }

  for (int pass = 0; pass < 2; ++pass) {
    for (int tile = 0; tile < 32; ++tile) {
      __syncthreads();
      if constexpr (F == 64) {
#pragma unroll
        for (int p = 0; p < 4; ++p) {
          int id = t + p * 256;
          int r = id >> 3, c = id & 7;
          *(bf16x8*)&chi[r * FPS + c * 8] =
              *(const bf16x8*)(hib + (size_t)(tile * 128 + r) * 64 + c * 8);
          *(bf16x8*)&clo[r * FPS + c * 8] =
              *(const bf16x8*)(lob + (size_t)(tile * 128 + r) * 64 + c * 8);
        }
        if (t < 128) csq[t] = sqb[tile * 128 + t];
      } else {
        if (t < 128) {
          *(bf16x8*)&chi[t * 8] = *(const bf16x8*)(hib + (size_t)(tile * 128 + t) * 8);
          *(bf16x8*)&clo[t * 8] = *(const bf16x8*)(lob + (size_t)(tile * 128 + t) * 8);
          csq[t] = sqb[tile * 128 + t];
        }
      }
      __syncthreads();

#pragma unroll 2
      for (int sub = 0; sub < 8; ++sub) {
        const int jl = sub * 16 + l16;
        f32x4 acc = {0.f, 0.f, 0.f, 0.f};
        if constexpr (F == 64) {
          bf16x8 bh0 = *(const bf16x8*)&chi[jl * FPS + quad * 8];
          bf16x8 bh1 = *(const bf16x8*)&chi[jl * FPS + 32 + quad * 8];
          bf16x8 bl0 = *(const bf16x8*)&clo[jl * FPS + quad * 8];
          bf16x8 bl1 = *(const bf16x8*)&clo[jl * FPS + 32 + quad * 8];
          acc = __builtin_amdgcn_mfma_f32_16x16x32_bf16(ahi[0], bh0, acc, 0, 0, 0);
          acc = __builtin_amdgcn_mfma_f32_16x16x32_bf16(ahi[1], bh1, acc, 0, 0, 0);
          acc = __builtin_amdgcn_mfma_f32_16x16x32_bf16(ahi[0], bl0, acc, 0, 0, 0);
          acc = __builtin_amdgcn_mfma_f32_16x16x32_bf16(ahi[1], bl1, acc, 0, 0, 0);
          acc = __builtin_amdgcn_mfma_f32_16x16x32_bf16(alo[0], bh0, acc, 0, 0, 0);
          acc = __builtin_amdgcn_mfma_f32_16x16x32_bf16(alo[1], bh1, acc, 0, 0, 0);
        } else {
          bf16x8 bh = (quad == 0) ? *(const bf16x8*)&chi[jl * 8] : z8;
          bf16x8 bl = (quad == 0) ? *(const bf16x8*)&clo[jl * 8] : z8;
          acc = __builtin_amdgcn_mfma_f32_16x16x32_bf16(ahi[0], bh, acc, 0, 0, 0);
          acc = __builtin_amdgcn_mfma_f32_16x16x32_bf16(ahi[0], bl, acc, 0, 0, 0);
          acc = __builtin_amdgcn_mfma_f32_16x16x32_bf16(alo[0], bh, acc, 0, 0, 0);
        }
        const float cs = csq[jl];
        const int jg = tile * 128 + jl;
#pragma unroll
        for (int reg = 0; reg < 4; ++reg) {   // C/D: col=l16 (cand), row=quad*4+reg
          float d = fmaf(-2.f, acc[reg], sqi4[reg] + cs);
          if (pass == 0) {
            float lo_ = fminf(d, t1[reg]);
            float hi_ = fmaxf(d, t1[reg]);
            t1[reg] = lo_;
            t2[reg] = fminf(t2[reg], hi_);
          } else {
            bool keep = d <= tinf4[reg];
            unsigned long long mask = __ballot(keep);
            unsigned qm = (unsigned)((mask >> (quad * 16)) & 0xFFFFULL);
            int rank = __popc(qm & ((1u << l16) - 1u));
            if (keep) {
              int pos = cnt4[reg] + rank;
              if (pos < CAP)
                glist[(size_t)(base + i0w + quad * 4 + reg) * CAP + pos] =
                    (ushort_t)jg;
            }
            cnt4[reg] += __popc(qm);
          }
        }
      }
    }
    if (pass == 0) {
#pragma unroll
      for (int reg = 0; reg < 4; ++reg) {
        float v = t2[reg];
#pragma unroll
        for (int off = 1; off < 16; off <<= 1)
          v = fmaxf(v, __shfl_xor(v, off, 64));       // within-quad reduce
        float eps = 6e-5f * (sqi4[reg] + sqm) + 1e-5f;
        tinf4[reg] = v + 2.f * eps;
      }
    }
  }

  if (l16 == 0) {
#pragma unroll
    for (int reg = 0; reg < 4; ++reg)
      gcnt[base + i0w + quad * 4 + reg] = cnt4[reg];
  }
}

// =====================================================================
// Rerank (R8/R9-validated): one wave per row. Exact fp32 distances
// (bit-identical chains) on survivors; exact lex-(dist,idx) top-32 SET
// via 44-bit radix-select. Overflow (n > CAP) -> full exact scan with
// validated ballot-insert (rare).
// =====================================================================
template <int F>
__global__ __launch_bounds__(256, 4)
void knn_rerank(const float* __restrict__ x, const float* __restrict__ sq,
                const int* __restrict__ gcnt,
                const ushort_t* __restrict__ glist,
                ushort_t* __restrict__ idx_out) {
  const int t = threadIdx.x, wave = t >> 6, lane = t & 63;
  const int row = blockIdx.x * 4 + wave;      // 0..32767
  const int b = row >> 12;
  const int i = row & (NPTS - 1);
  const float* xb  = x + (size_t)b * NPTS * F;
  const float* sqb = sq + ((size_t)b << 12);
  const float sqi = sqb[i];

  float4 q[(F == 64) ? 16 : 1];
  float qx = 0.f, qy = 0.f, qz = 0.f;
  if constexpr (F == 64) {
#pragma unroll
    for (int c4 = 0; c4 < 16; ++c4)
      q[c4] = *(const float4*)(xb + (size_t)i * 64 + c4 * 4);
  } else {
    qx = xb[(size_t)i * 3 + 0];
    qy = xb[(size_t)i * 3 + 1];
    qz = xb[(size_t)i * 3 + 2];
  }

  const int n = gcnt[row];

  if (n <= CAP) {
    unsigned long long vk[3];
#pragma unroll
    for (int s = 0; s < 3; ++s) {
      int li = s * 64 + lane;
      unsigned long long v = 0xFFFFFFFFFFFULL;        // sentinel > any real
      if (li < n) {
        int j = glist[(size_t)row * CAP + li];
        float d;
        if constexpr (F == 64) {
          const float4* xj = (const float4*)(xb + (size_t)j * 64);
          float dot = 0.f;
#pragma unroll
          for (int c4 = 0; c4 < 16; ++c4) {
            float4 c = xj[c4];
            dot = fmaf(q[c4].x, c.x, dot);
            dot = fmaf(q[c4].y, c.y, dot);
            dot = fmaf(q[c4].z, c.z, dot);
            dot = fmaf(q[c4].w, c.w, dot);
          }
          d = fmaf(-2.f, dot, sqi + sqb[j]);
        } else {
          const float* xj = xb + (size_t)j * 3;
          float dot = fmaf(qz, xj[2], fmaf(qy, xj[1], qx * xj[0]));
          d = fmaf(-2.f, dot, sqi + sqb[j]);
        }
        unsigned u  = __float_as_uint(d);
        unsigned ck = (u & 0x80000000u) ? ~u : (u | 0x80000000u);
        v = ((unsigned long long)ck << 12) | (unsigned)j;
      }
      vk[s] = v;
    }
    // radix-select: prefix ends as the exact 32nd-smallest value (distinct)
    unsigned long long prefix = 0;
    int need = 32;
    for (int bit = 43; bit >= 0; --bit) {
      unsigned long long hm = (bit == 43) ? 0ULL
          : (~((1ULL << (bit + 1)) - 1ULL) & 0xFFFFFFFFFFFULL);
      int cnt0 = 0;
#pragma unroll
      for (int s = 0; s < 3; ++s) {
        bool a = ((vk[s] ^ prefix) & hm) == 0ULL;
        bool z = ((vk[s] >> bit) & 1ULL) == 0ULL;
        cnt0 += (int)__popcll(__ballot(a && z));
      }
      if (cnt0 < need) { need -= cnt0; prefix |= 1ULL << bit; }
    }
    int prev = 0;
#pragma unroll
    for (int s = 0; s < 3; ++s) {
      bool sel = vk[s] <= prefix;
      unsigned long long m = __ballot(sel);
      int rank = (int)__popcll(m & ((1ULL << lane) - 1ULL));
      if (sel)
        idx_out[(size_t)row * KNN + prev + rank] =
            (ushort_t)(vk[s] & 0xFFFULL);
      prev += (int)__popcll(m);
    }
  } else {
    // fallback: exact full scan, validated ballot-insert
    unsigned long long ent = (0xFFFFFFFFFFFULL << 5) | (unsigned long long)(lane & 31);
    unsigned long long M   = (0xFFFFFFFFFFFULL << 5) | 31ULL;
    for (int c0 = 0; c0 < NPTS; c0 += 64) {
      const int j = c0 + lane;
      float d;
      if constexpr (F == 64) {
        const float4* xj = (const float4*)(xb + (size_t)j * 64);
        float dot = 0.f;
#pragma unroll
        for (int c4 = 0; c4 < 16; ++c4) {
          float4 c = xj[c4];
          dot = fmaf(q[c4].x, c.x, dot);
          dot = fmaf(q[c4].y, c.y, dot);
          dot = fmaf(q[c4].z, c.z, dot);
          dot = fmaf(q[c4].w, c.w, dot);
        }
        d = fmaf(-2.f, dot, sqi + sqb[j]);
      } else {
        const float* xj = xb + (size_t)j * 3;
        float dot = fmaf(qz, xj[2], fmaf(qy, xj[1], qx * xj[0]));
        d = fmaf(-2.f, dot, sqi + sqb[j]);
      }
      unsigned u  = __float_as_uint(d);
      unsigned ck = (u & 0x80000000u) ? ~u : (u | 0x80000000u);
      unsigned long long cq = ((unsigned long long)ck << 12) | (unsigned)j;
      unsigned long long mask = __ballot(cq < (M >> 5));
      while (mask) {
        const int src = __builtin_ctzll(mask);
        mask &= mask - 1;
        const unsigned long long bq = shfl_u64(cq, src);
        if (bq < (M >> 5)) {
          const unsigned slot = (unsigned)(M & 31ULL);
          if ((unsigned)(lane & 31) == slot) ent = (bq << 5) | slot;
          unsigned long long v = ent;
#pragma unroll
          for (int off = 16; off >= 1; off >>= 1) {
            unsigned long long w2 = shfl_xor_u64(v, off);
            v = (v > w2) ? v : w2;
          }
          M = v;
        }
      }
    }
    if (lane < 32)
      idx_out[(size_t)row * KNN + lane] =
          (ushort_t)((ent >> 5) & 0xFFFULL);
  }
}

// ---------------- per-node P = x.Wbot ; C = x.(Wtop-Wbot) + b ----------------
__global__ __launch_bounds__(256) void mlp_pc_kernel(const float* __restrict__ xin,
                                                     const float* __restrict__ W,
                                                     const float* __restrict__ bias,
                                                     float* __restrict__ P,
                                                     float* C,
                                                     int F, int O, int total) {
  int t = blockIdx.x * 256 + threadIdx.x;
  if (t >= total) return;
  int n = t / O, o = t % O;
  const float* xr = xin + (size_t)n * F;
  const float* Wt = W + o;
  const float* Wb = W + (size_t)F * O + o;
  float p = 0.f, c = 0.f;
  for (int f = 0; f < F; ++f) {
    float a  = xr[f];
    float wt = Wt[(size_t)f * O];
    float wb = Wb[(size_t)f * O];
    p = fmaf(a, wb, p);
    c = fmaf(a, wt - wb, c);
  }
  P[t] = p;
  C[t] = c + bias[o];
}

// ---------------- fused: h += max_k P[idx_k]  +  BN partial sums (O=64) -----
// channel == lane; per-lane double accumulators; per-block double2 partials.
__global__ __launch_bounds__(256, 8)
void aggregate_bn_kernel(const ushort_t* __restrict__ idx,
                         const float* __restrict__ P,
                         float* h, double2* __restrict__ partial) {
  const int t = threadIdx.x, wave = t >> 6, lane = t & 63;
  double s = 0.0, s2 = 0.0;
  for (int r = blockIdx.x * 4 + wave; r < NROWS; r += 16384) {
    const ushort_t* ix = idx + (size_t)r * KNN;
    const int rowbase = (r >> 12) << 12;
    float m = -3.402823466e+38f;
#pragma unroll 8
    for (int k = 0; k < KNN; ++k) {
      int jg = rowbase + ix[k];
      m = fmaxf(m, P[(size_t)jg * 64 + lane]);
    }
    float hv = h[(size_t)r * 64 + lane] + m;
    h[(size_t)r * 64 + lane] = hv;
    float v = fmaxf(hv, 0.f);
    s += v;
    s2 += (double)v * v;
  }
  __shared__ double ls[4][64], ls2[4][64];
  ls[wave][lane] = s;
  ls2[wave][lane] = s2;
  __syncthreads();
  if (wave == 0) {
    double a = ls[0][lane] + ls[1][lane] + ls[2][lane] + ls[3][lane];
    double bb = ls2[0][lane] + ls2[1][lane] + ls2[2][lane] + ls2[3][lane];
    double2 o; o.x = a; o.y = bb;
    partial[blockIdx.x * 64 + lane] = o;
  }
}

// ---------------- BN finalize: 64 blocks, one channel each ----------------
__global__ __launch_bounds__(64) void bn_finalize_kernel(const double2* __restrict__ partial,
                                                         float* __restrict__ stats) {
  const int c = blockIdx.x, t = threadIdx.x;
  double s = 0.0, s2 = 0.0;
  for (int p = t; p < 4096; p += 64) {
    double2 v = partial[p * 64 + c];
    s += v.x;
    s2 += v.y;
  }
  __shared__ double ss[64], ss2[64];
  ss[t] = s; ss2[t] = s2;
  __syncthreads();
  for (int st = 32; st; st >>= 1) {
    if (t < st) { ss[t] += ss[t + st]; ss2[t] += ss2[t + st]; }
    __syncthreads();
  }
  if (t == 0) {
    double mean = ss[0] / (double)NROWS;
    double var  = ss2[0] / (double)NROWS - mean * mean;
    stats[c]      = (float)mean;
    stats[64 + c] = (float)(1.0 / sqrt(var + 1e-5));
  }
}

// ---------------- fused: BN apply + hi/lo bf16 split of the output ----------
__global__ __launch_bounds__(256) void bn_apply_fused(const float* h,
                                                      const float* __restrict__ stats,
                                                      const float* __restrict__ g,
                                                      const float* __restrict__ be,
                                                      float* out,
                                                      ushort_t* __restrict__ hi,
                                                      ushort_t* __restrict__ lo,
                                                      int total) {
  int t = blockIdx.x * 256 + threadIdx.x;
  if (t >= total) return;
  int ch = t & 63;
  float v = fmaxf(h[t], 0.f);
  float o = (v - stats[ch]) * stats[64 + ch] * g[ch] + be[ch];
  out[t] = o;
  ushort_t hh = bf16_rne(o);
  float hf = __uint_as_float((unsigned)hh << 16);
  ushort_t ll = bf16_rne(o - hf);
  hi[t] = hh;
  lo[t] = ll;
}

// ---------------- plain aggregate for O=3 (layer 3) ----------------
__global__ __launch_bounds__(256) void aggregate_kernel(const ushort_t* __restrict__ idx,
                                                        const float* __restrict__ P,
                                                        float* h, int O, int total) {
  int t = blockIdx.x * 256 + threadIdx.x;
  if (t >= total) return;
  int n = t / O, o = t % O;
  const ushort_t* ix = idx + (size_t)n * KNN;
  const int rowbase = (n >> 12) << 12;
  float m = -3.402823466e+38f;
  for (int k = 0; k < KNN; ++k) {
    int jg = rowbase + ix[k];
    float v = P[(size_t)jg * O + o];
    m = fmaxf(m, v);
  }
  h[t] = h[t] + m;
}

// ---------------- write h3 to out + per-block loss partials ----------------
__global__ __launch_bounds__(256) void final_kernel(const float* __restrict__ h3,
                                                    const float* __restrict__ target,
                                                    float* __restrict__ out,
                                                    double* __restrict__ partial) {
  double s = 0.0;
  for (int t = blockIdx.x * 256 + threadIdx.x; t < NROWS * 3; t += 256 * 256) {
    float v = h3[t];
    out[t] = v;
    float d = v - target[t];
    s += (double)d * d;
  }
  __shared__ double ls[256];
  int t = threadIdx.x;
  ls[t] = s;
  __syncthreads();
  for (int st = 128; st; st >>= 1) {
    if (t < st) ls[t] += ls[t + st];
    __syncthreads();
  }
  if (t == 0) partial[blockIdx.x] = ls[0];
}

__global__ __launch_bounds__(256) void loss_kernel(const double* __restrict__ partial,
                                                   float* __restrict__ out) {
  int t = threadIdx.x;
  __shared__ double ls[256];
  ls[t] = partial[t];
  __syncthreads();
  for (int st = 128; st; st >>= 1) {
    if (t < st) ls[t] += ls[t + st];
    __syncthreads();
  }
  if (t == 0) out[NROWS * 3] = (float)(ls[0] / (double)(NROWS * 3));
}

// ---------------- driver ----------------
extern "C" void kernel_launch(void* const* d_in, const int* in_sizes, int n_in,
                              void* d_out, int out_size, void* d_ws, size_t ws_size,
                              hipStream_t stream) {
  const float* x   = (const float*)d_in[0];
  const float* tgt = (const float*)d_in[1];
  const float* W1  = (const float*)d_in[2];
  const float* b1  = (const float*)d_in[3];
  const float* g1  = (const float*)d_in[4];
  const float* be1 = (const float*)d_in[5];
  const float* W2  = (const float*)d_in[6];
  const float* b2  = (const float*)d_in[7];
  const float* g2  = (const float*)d_in[8];
  const float* be2 = (const float*)d_in[9];
  const float* W3  = (const float*)d_in[10];
  const float* b3  = (const float*)d_in[11];
  float* out = (float*)d_out;

  char* ws = (char*)d_ws;
  size_t off = 0;
  float* sq    = (float*)(ws + off); off += (size_t)NROWS * 4;           // 128 KB
  ushort_t* idxb = (ushort_t*)(ws + off); off += (size_t)NROWS * KNN * 2; // 2 MB
  float* P     = (float*)(ws + off); off += (size_t)NROWS * 64 * 4;      // 8 MB
  float* CA    = (float*)(ws + off); off += (size_t)NROWS * 64 * 4;      // 8 MB
  float* CB    = (float*)(ws + off); off += (size_t)NROWS * 64 * 4;      // 8 MB
  int*   gcnt  = (int*)(ws + off);   off += (size_t)NROWS * 4;           // 128 KB
  ushort_t* glist = (ushort_t*)(ws + off); off += (size_t)NROWS * CAP * 2; // 12.6 MB
  float* stats = (float*)(ws + off); off += 256 * 4;
  float* sqmax = (float*)(ws + off); off += 64;
  double* part = (double*)(ws + off); off += 256 * 8;

  // Aliases (lifetime-disjoint):
  ushort_t* hi64 = (ushort_t*)P;                 // bf16 hi/lo live bn_apply_fused -> screen/rerank
  ushort_t* lo64 = hi64 + (size_t)NROWS * 64;
  ushort_t* hi3 = (ushort_t*)CB;                 // padded F=3 split, layer 1 only
  ushort_t* lo3 = hi3 + (size_t)NROWS * 8;
  double2* partBN = (double2*)glist;             // 4 MB (4096 blocks x 64 x 16B) <= 12.6 MB

  const int T64 = NROWS * 64;
  const int T3  = NROWS * 3;

  // ---- layer 1 (F=3 -> 64), MFMA screen + exact rerank ----
  sqnorm_kernel<<<NROWS / 256, 256, 0, stream>>>(x, sq, 3);
  prep3_kernel<<<NROWS / 256, 256, 0, stream>>>(x, hi3, lo3);
  batchmax_kernel<<<NB, 256, 0, stream>>>(sq, sqmax);
  knn_screen<3><<<512, 256, 0, stream>>>(hi3, lo3, sq, sqmax, gcnt, glist);
  knn_rerank<3><<<NROWS / 4, 256, 0, stream>>>(x, sq, gcnt, glist, idxb);
  mlp_pc_kernel<<<T64 / 256, 256, 0, stream>>>(x, W1, b1, P, CA, 3, 64, T64);
  aggregate_bn_kernel<<<4096, 256, 0, stream>>>(idxb, P, CA, partBN);
  bn_finalize_kernel<<<64, 64, 0, stream>>>(partBN, stats);
  bn_apply_fused<<<T64 / 256, 256, 0, stream>>>(CA, stats, g1, be1, CA, hi64, lo64, T64);

  // ---- layer 2 (F=64 -> 64), MFMA screen + exact rerank ----
  sqnorm_kernel<<<NROWS / 256, 256, 0, stream>>>(CA, sq, 64);
  batchmax_kernel<<<NB, 256, 0, stream>>>(sq, sqmax);
  knn_screen<64><<<512, 256, 0, stream>>>(hi64, lo64, sq, sqmax, gcnt, glist);
  knn_rerank<64><<<NROWS / 4, 256, 0, stream>>>(CA, sq, gcnt, glist, idxb);
  mlp_pc_kernel<<<T64 / 256, 256, 0, stream>>>(CA, W2, b2, P, CB, 64, 64, T64);
  aggregate_bn_kernel<<<4096, 256, 0, stream>>>(idxb, P, CB, partBN);
  bn_finalize_kernel<<<64, 64, 0, stream>>>(partBN, stats);
  bn_apply_fused<<<T64 / 256, 256, 0, stream>>>(CB, stats, g2, be2, CB, hi64, lo64, T64);

  // ---- layer 3 (F=64 -> 3), MFMA screen + exact rerank ----
  sqnorm_kernel<<<NROWS / 256, 256, 0, stream>>>(CB, sq, 64);
  batchmax_kernel<<<NB, 256, 0, stream>>>(sq, sqmax);
  knn_screen<64><<<512, 256, 0, stream>>>(hi64, lo64, sq, sqmax, gcnt, glist);
  knn_rerank<64><<<NROWS / 4, 256, 0, stream>>>(CB, sq, gcnt, glist, idxb);
  mlp_pc_kernel<<<T3 / 256, 256, 0, stream>>>(CB, W3, b3, P, CA, 64, 3, T3);
  aggregate_kernel<<<T3 / 256, 256, 0, stream>>>(idxb, P, CA, 3, T3);

  // ---- output + loss ----
  final_kernel<<<256, 256, 0, stream>>>(CA, tgt, out, part);
  loss_kernel<<<1, 256, 0, stream>>>(part, out);
}